// Round 3
// baseline (807.347 us; speedup 1.0000x reference)
//
#include <hip/hip_runtime.h>
#include <hip/hip_cooperative_groups.h>
#include <math.h>

namespace cg = cooperative_groups;

// GCN is linear: out = (((z3^T X) W1 + s2 b1) W2 + s1 b2) W3 + N b3) / sqrt(N)
// z1 = M^T 1, z2 = M^T z1, z3 = M^T z2, s1 = sum(z1), s2 = sum(z2),
// M = D^{-1/2}(A+I)D^{-1/2}.  Single cooperative kernel; grid.sync() between
// phases replaces 10 separate graph nodes.

#define TPB 256
#define NBLK 512

__global__ __launch_bounds__(TPB) void k_fused(
    const int* __restrict__ src, const int* __restrict__ dst,
    const float* __restrict__ X, const float* __restrict__ Ws,
    const float* __restrict__ bs, float* __restrict__ out,
    float* __restrict__ deg,       // [N], becomes dinv in-place
    float* __restrict__ sig,       // [2]
    float* __restrict__ z1, float* __restrict__ z2, float* __restrict__ z3,
    float* __restrict__ w,         // [E]
    float* __restrict__ partials,  // [NBLK*128]
    int N, int E)
{
    cg::grid_group grid = cg::this_grid();
    const int tid = blockIdx.x * blockDim.x + threadIdx.x;
    const int T   = gridDim.x * blockDim.x;
    const int t   = threadIdx.x;
    const int E4  = E >> 2;

    __shared__ float  red[TPB];
    __shared__ float4 red4[TPB];
    __shared__ float  uv[128];

    // ph0: zero deg + sig (workspace is poisoned 0xAA every call)
    for (int i = tid; i < N; i += T) deg[i] = 0.0f;
    if (tid < 2) sig[tid] = 0.0f;
    grid.sync();

    // ph1: degree counts via atomics on dst
    for (int c = tid; c < E4; c += T) {
        int4 d4 = ((const int4*)dst)[c];
        atomicAdd(&deg[d4.x], 1.0f);
        atomicAdd(&deg[d4.y], 1.0f);
        atomicAdd(&deg[d4.z], 1.0f);
        atomicAdd(&deg[d4.w], 1.0f);
    }
    for (int e = (E4 << 2) + tid; e < E; e += T) atomicAdd(&deg[dst[e]], 1.0f);
    grid.sync();

    // ph2: dinv in-place; z1 self term = dinv^2
    for (int i = tid; i < N; i += T) {
        float dv = (float)(1.0 / sqrt((double)deg[i] + 1.0));
        deg[i] = dv;
        z1[i]  = dv * dv;
    }
    grid.sync();

    const float* dinv = deg;

    // ph3: edge weights w = dinv[s]*dinv[d]; z1[s] += w
    for (int c = tid; c < E4; c += T) {
        int4 s4 = ((const int4*)src)[c];
        int4 d4 = ((const int4*)dst)[c];
        float4 w4;
        w4.x = dinv[s4.x] * dinv[d4.x];
        w4.y = dinv[s4.y] * dinv[d4.y];
        w4.z = dinv[s4.z] * dinv[d4.z];
        w4.w = dinv[s4.w] * dinv[d4.w];
        ((float4*)w)[c] = w4;
        atomicAdd(&z1[s4.x], w4.x);
        atomicAdd(&z1[s4.y], w4.y);
        atomicAdd(&z1[s4.z], w4.z);
        atomicAdd(&z1[s4.w], w4.w);
    }
    for (int e = (E4 << 2) + tid; e < E; e += T) {
        float we = dinv[src[e]] * dinv[dst[e]];
        w[e] = we;
        atomicAdd(&z1[src[e]], we);
    }
    grid.sync();

    // ph4: s1 = sum(z1); z2 self term
    {
        float acc = 0.0f;
        for (int i = tid; i < N; i += T) {
            float v  = z1[i];
            float dv = dinv[i];
            z2[i] = dv * dv * v;
            acc += v;
        }
        red[t] = acc;
        __syncthreads();
        for (int s = TPB / 2; s > 0; s >>= 1) {
            if (t < s) red[t] += red[t + s];
            __syncthreads();
        }
        if (t == 0) atomicAdd(&sig[0], red[0]);
    }
    grid.sync();

    // ph5: z2[s] += w * z1[d]
    for (int c = tid; c < E4; c += T) {
        int4 s4 = ((const int4*)src)[c];
        int4 d4 = ((const int4*)dst)[c];
        float4 w4 = ((const float4*)w)[c];
        atomicAdd(&z2[s4.x], w4.x * z1[d4.x]);
        atomicAdd(&z2[s4.y], w4.y * z1[d4.y]);
        atomicAdd(&z2[s4.z], w4.z * z1[d4.z]);
        atomicAdd(&z2[s4.w], w4.w * z1[d4.w]);
    }
    for (int e = (E4 << 2) + tid; e < E; e += T)
        atomicAdd(&z2[src[e]], w[e] * z1[dst[e]]);
    grid.sync();

    // ph6: s2 = sum(z2); z3 self term
    {
        float acc = 0.0f;
        for (int i = tid; i < N; i += T) {
            float v  = z2[i];
            float dv = dinv[i];
            z3[i] = dv * dv * v;
            acc += v;
        }
        red[t] = acc;
        __syncthreads();
        for (int s = TPB / 2; s > 0; s >>= 1) {
            if (t < s) red[t] += red[t + s];
            __syncthreads();
        }
        if (t == 0) atomicAdd(&sig[1], red[0]);
    }
    grid.sync();

    // ph7: z3[s] += w * z2[d]
    for (int c = tid; c < E4; c += T) {
        int4 s4 = ((const int4*)src)[c];
        int4 d4 = ((const int4*)dst)[c];
        float4 w4 = ((const float4*)w)[c];
        atomicAdd(&z3[s4.x], w4.x * z2[d4.x]);
        atomicAdd(&z3[s4.y], w4.y * z2[d4.y]);
        atomicAdd(&z3[s4.z], w4.z * z2[d4.z]);
        atomicAdd(&z3[s4.w], w4.w * z2[d4.w]);
    }
    for (int e = (E4 << 2) + tid; e < E; e += T)
        atomicAdd(&z3[src[e]], w[e] * z2[dst[e]]);
    grid.sync();

    // ph8: partials[b][0:128] = sum_r z3[r] * X[r][0:128] (block-strided rows)
    {
        int c4 = (t & 31) * 4;
        int rg = t >> 5;
        float4 a = make_float4(0.f, 0.f, 0.f, 0.f);
        for (int r = blockIdx.x * 8 + rg; r < N; r += gridDim.x * 8) {
            float zv = z3[r];
            const float4 xv = *(const float4*)(X + (size_t)r * 128 + c4);
            a.x += zv * xv.x; a.y += zv * xv.y;
            a.z += zv * xv.z; a.w += zv * xv.w;
        }
        red4[t] = a;
        __syncthreads();
        if (t < 32) {
            float4 s = red4[t];
            #pragma unroll
            for (int g = 1; g < 8; ++g) {
                float4 b = red4[t + 32 * g];
                s.x += b.x; s.y += b.y; s.z += b.z; s.w += b.w;
            }
            float* p = partials + (size_t)blockIdx.x * 128 + c4;
            p[0] = s.x; p[1] = s.y; p[2] = s.z; p[3] = s.w;
        }
    }
    grid.sync();

    // ph9: block 0 reduces partials and runs the 128-wide 3-layer chain
    if (blockIdx.x == 0) {
        int j = t & 127, g = t >> 7;        // g in {0,1}
        float a = 0.0f;
        for (int b = g; b < (int)gridDim.x; b += 2)
            a += partials[(size_t)b * 128 + j];
        red[t] = a;
        __syncthreads();
        if (t < 128) uv[t] = red[t] + red[t + 128];
        __syncthreads();
        float s1 = sig[0], s2 = sig[1];
        for (int l = 0; l < 3; ++l) {
            const float* W = Ws + (size_t)l * 16384;
            float a2 = 0.0f;
            #pragma unroll 8
            for (int kk = 0; kk < 64; ++kk) {
                int k = g * 64 + kk;
                a2 += uv[k] * W[k * 128 + j];
            }
            red[t] = a2;
            __syncthreads();
            float nv = 0.0f;
            if (t < 128) {
                float s = red[t] + red[t + 128];
                float coef = (l == 0) ? s2 : (l == 1) ? s1 : (float)N;
                nv = s + coef * bs[l * 128 + t];
            }
            __syncthreads();
            if (t < 128) uv[t] = nv;
            __syncthreads();
        }
        if (t < 128) out[t] = uv[t] * (float)(1.0 / sqrt((double)N));
    }
}

extern "C" void kernel_launch(void* const* d_in, const int* in_sizes, int n_in,
                              void* d_out, int out_size, void* d_ws, size_t ws_size,
                              hipStream_t stream) {
    const int*   ei = (const int*)d_in[0];
    const float* X  = (const float*)d_in[1];
    const float* Ws = (const float*)d_in[2];
    const float* bs = (const float*)d_in[3];
    float* out = (float*)d_out;

    int E = in_sizes[0] / 2;
    int N = in_sizes[1] / 128;
    const int* src = ei;
    const int* dst = ei + E;

    float* ws       = (float*)d_ws;
    float* deg      = ws;                            // [N]
    float* sig      = ws + N;                        // [2] (+2 pad)
    float* z1       = ws + N + 4;                    // [N]
    float* z2       = z1 + N;                        // [N]
    float* z3       = z2 + N;                        // [N]
    float* partials = z3 + N;                        // [NBLK*128]
    float* w        = partials + NBLK * 128;         // [E]

    void* args[] = { (void*)&src, (void*)&dst, (void*)&X, (void*)&Ws, (void*)&bs,
                     (void*)&out, (void*)&deg, (void*)&sig, (void*)&z1, (void*)&z2,
                     (void*)&z3, (void*)&w, (void*)&partials, (void*)&N, (void*)&E };
    hipLaunchCooperativeKernel((void*)k_fused, dim3(NBLK), dim3(TPB), args, 0, stream);
}

// Round 4
// 257.958 us; speedup vs baseline: 3.1298x; 3.1298x over previous
//
#include <hip/hip_runtime.h>
#include <math.h>

// GCN is linear: out = (((z3^T X) W1 + s2 b1) W2 + s1 b2) W3 + N b3) / sqrt(N)
// z1 = M^T 1, z2 = M^T z1, z3 = M^T z2, s1 = sum(z1), s2 = sum(z2),
// M = D^{-1/2}(A+I)D^{-1/2}.  Multi-kernel (kernel boundaries are the cheap
// sync on gfx950 — cooperative grid.sync() cost 3x due to cross-XCD L2
// flushes, measured round 3).  Self-terms + s1/s2 sums are fused into the
// edge-scatter passes against pre-zeroed z2/z3.

#define TPB 256
#define WSUM_BLOCKS 512

__global__ void k_deg(const int* __restrict__ dst, float* __restrict__ deg, int E) {
    int i = blockIdx.x * blockDim.x + threadIdx.x;
    int e0 = i * 4;
    if (e0 + 3 < E) {
        int4 d4 = *(const int4*)(dst + e0);
        atomicAdd(&deg[d4.x], 1.0f);
        atomicAdd(&deg[d4.y], 1.0f);
        atomicAdd(&deg[d4.z], 1.0f);
        atomicAdd(&deg[d4.w], 1.0f);
    } else {
        for (int e = e0; e < E; ++e) atomicAdd(&deg[dst[e]], 1.0f);
    }
}

// deg (counts) -> dinv in place; z1 init = self term dinv^2
__global__ void k_dinv_z1(float* __restrict__ degdinv, float* __restrict__ z1, int N) {
    int i = blockIdx.x * blockDim.x + threadIdx.x;
    if (i < N) {
        float dv = (float)(1.0 / sqrt((double)degdinv[i] + 1.0));
        degdinv[i] = dv;
        z1[i] = dv * dv;
    }
}

// Pass 1: w[e] = dinv[src]*dinv[dst]; z1[src] += w[e]
__global__ void k_edge1(const int* __restrict__ src, const int* __restrict__ dst,
                        const float* __restrict__ dinv, float* __restrict__ w,
                        float* __restrict__ z1, int E) {
    int i = blockIdx.x * blockDim.x + threadIdx.x;
    int e0 = i * 4;
    if (e0 + 3 < E) {
        int4 s4 = *(const int4*)(src + e0);
        int4 d4 = *(const int4*)(dst + e0);
        float4 w4;
        w4.x = dinv[s4.x] * dinv[d4.x];
        w4.y = dinv[s4.y] * dinv[d4.y];
        w4.z = dinv[s4.z] * dinv[d4.z];
        w4.w = dinv[s4.w] * dinv[d4.w];
        *(float4*)(w + e0) = w4;
        atomicAdd(&z1[s4.x], w4.x);
        atomicAdd(&z1[s4.y], w4.y);
        atomicAdd(&z1[s4.z], w4.z);
        atomicAdd(&z1[s4.w], w4.w);
    } else {
        for (int e = e0; e < E; ++e) {
            float we = dinv[src[e]] * dinv[dst[e]];
            w[e] = we;
            atomicAdd(&z1[src[e]], we);
        }
    }
}

// Passes 2,3 fused with self-term and sum:
//   zout[src] += w[e]*zin[dst]          (zout pre-zeroed)
//   zout[i]   += dinv[i]^2 * zin[i]     (atomic, races with edge adds are fine)
//   *sig      += sum(zin)
__global__ void k_edgeself(const int* __restrict__ src, const int* __restrict__ dst,
                           const float* __restrict__ w, const float* __restrict__ dinv,
                           const float* __restrict__ zin, float* __restrict__ zout,
                           float* __restrict__ sig, int N, int E) {
    int tid = blockIdx.x * blockDim.x + threadIdx.x;
    int T = gridDim.x * blockDim.x;
    int e0 = tid * 4;
    if (e0 + 3 < E) {
        int4 s4 = *(const int4*)(src + e0);
        int4 d4 = *(const int4*)(dst + e0);
        float4 w4 = *(const float4*)(w + e0);
        atomicAdd(&zout[s4.x], w4.x * zin[d4.x]);
        atomicAdd(&zout[s4.y], w4.y * zin[d4.y]);
        atomicAdd(&zout[s4.z], w4.z * zin[d4.z]);
        atomicAdd(&zout[s4.w], w4.w * zin[d4.w]);
    } else {
        for (int e = e0; e < E; ++e)
            atomicAdd(&zout[src[e]], w[e] * zin[dst[e]]);
    }
    // self term + sum(zin), grid-strided over N
    float acc = 0.0f;
    for (int i = tid; i < N; i += T) {
        float v = zin[i];
        float dv = dinv[i];
        atomicAdd(&zout[i], dv * dv * v);
        acc += v;
    }
    __shared__ float red[TPB];
    red[threadIdx.x] = acc;
    __syncthreads();
    for (int s = TPB / 2; s > 0; s >>= 1) {
        if (threadIdx.x < s) red[threadIdx.x] += red[threadIdx.x + s];
        __syncthreads();
    }
    if (threadIdx.x == 0) atomicAdd(sig, red[0]);
}

// partials[b][0:128] = sum over this block's rows of z[r] * X[r][0:128]
__global__ void k_wsum(const float* __restrict__ x, const float* __restrict__ z,
                       float* __restrict__ partials, int N) {
    int tid = threadIdx.x;
    int c4 = (tid & 31) * 4;
    int rg = tid >> 5;
    float4 acc = make_float4(0.f, 0.f, 0.f, 0.f);
    for (int r = blockIdx.x * 8 + rg; r < N; r += gridDim.x * 8) {
        float zv = z[r];
        const float4 xv = *(const float4*)(x + (size_t)r * 128 + c4);
        acc.x += zv * xv.x; acc.y += zv * xv.y;
        acc.z += zv * xv.z; acc.w += zv * xv.w;
    }
    __shared__ float4 red[TPB];
    red[tid] = acc;
    __syncthreads();
    if (tid < 32) {
        float4 a = red[tid];
        #pragma unroll
        for (int g = 1; g < 8; ++g) {
            float4 b = red[tid + 32 * g];
            a.x += b.x; a.y += b.y; a.z += b.z; a.w += b.w;
        }
        float* p = partials + (size_t)blockIdx.x * 128 + c4;
        p[0] = a.x; p[1] = a.y; p[2] = a.z; p[3] = a.w;
    }
}

// 1024 threads: reduce partials -> u0, then 3-layer 128-wide chain with
// 8-way split-K (coalesced W reads, LDS tree reduce).
__global__ __launch_bounds__(1024) void k_final(
        const float* __restrict__ partials, int nb,
        const float* __restrict__ Ws, const float* __restrict__ bs,
        const float* __restrict__ sig, float* __restrict__ out, int N) {
    __shared__ float uv[128];
    __shared__ float red[1024];
    int t = threadIdx.x;
    int j = t & 127, g = t >> 7;            // g in [0,8)
    float acc = 0.0f;
    for (int b = g; b < nb; b += 8) acc += partials[(size_t)b * 128 + j];
    red[t] = acc;
    __syncthreads();
    if (t < 128) {
        float s = 0.0f;
        #pragma unroll
        for (int gg = 0; gg < 8; ++gg) s += red[t + 128 * gg];
        uv[t] = s;
    }
    __syncthreads();
    float s1 = sig[0], s2 = sig[1];
    for (int l = 0; l < 3; ++l) {
        const float* W = Ws + (size_t)l * 16384;
        float a = 0.0f;
        #pragma unroll
        for (int kk = 0; kk < 16; ++kk) {
            int k = g * 16 + kk;
            a += uv[k] * W[k * 128 + j];
        }
        red[t] = a;
        __syncthreads();
        float nv = 0.0f;
        if (t < 128) {
            float s = 0.0f;
            #pragma unroll
            for (int gg = 0; gg < 8; ++gg) s += red[t + 128 * gg];
            float coef = (l == 0) ? s2 : (l == 1) ? s1 : (float)N;
            nv = s + coef * bs[l * 128 + t];
        }
        __syncthreads();
        if (t < 128) uv[t] = nv;
        __syncthreads();
    }
    if (t < 128) out[t] = uv[t] * (float)(1.0 / sqrt((double)N));
}

extern "C" void kernel_launch(void* const* d_in, const int* in_sizes, int n_in,
                              void* d_out, int out_size, void* d_ws, size_t ws_size,
                              hipStream_t stream) {
    const int*   ei = (const int*)d_in[0];
    const float* X  = (const float*)d_in[1];
    const float* Ws = (const float*)d_in[2];
    const float* bs = (const float*)d_in[3];
    float* out = (float*)d_out;

    int E = in_sizes[0] / 2;
    int N = in_sizes[1] / 128;
    const int* src = ei;
    const int* dst = ei + E;

    // layout: [deg N][sig 4][z2 N][z3 N] <- zeroed in one memset
    //         [z1 N][w E][partials]
    float* ws       = (float*)d_ws;
    float* deg      = ws;                        // [N]
    float* sig      = ws + N;                    // [4]
    float* z2       = ws + N + 4;                // [N]
    float* z3       = z2 + N;                    // [N]
    float* z1       = z3 + N;                    // [N]
    float* w        = z1 + N;                    // [E]
    float* partials = w + E;                     // [WSUM_BLOCKS*128]

    hipMemsetAsync(d_ws, 0, (size_t)(3 * N + 4) * sizeof(float), stream);

    int gE4 = (E / 4 + TPB - 1) / TPB;   // 4 edges per thread
    int gN  = (N + TPB - 1) / TPB;

    k_deg     <<<gE4, TPB, 0, stream>>>(dst, deg, E);
    k_dinv_z1 <<<gN,  TPB, 0, stream>>>(deg, z1, N);
    k_edge1   <<<gE4, TPB, 0, stream>>>(src, dst, deg, w, z1, E);
    k_edgeself<<<gE4, TPB, 0, stream>>>(src, dst, w, deg, z1, z2, &sig[0], N, E);
    k_edgeself<<<gE4, TPB, 0, stream>>>(src, dst, w, deg, z2, z3, &sig[1], N, E);
    k_wsum    <<<WSUM_BLOCKS, TPB, 0, stream>>>(X, z3, partials, N);
    k_final   <<<1, 1024, 0, stream>>>(partials, WSUM_BLOCKS, Ws, bs, sig, out, N);
}